// Round 11
// baseline (482.096 us; speedup 1.0000x reference)
//
#include <hip/hip_runtime.h>
#include <hip/hip_bf16.h>

typedef __attribute__((ext_vector_type(8))) short short8;
typedef __attribute__((ext_vector_type(4))) short short4b;
typedef __attribute__((ext_vector_type(4))) float f32x4;

#define S_LEN 2048
#define DIM   64
#define NB    32
#define BR    64
#define BC    64
#define NKT   (S_LEN / BC)   // 32

#define KP   72   // K/Vt row pitch in shorts (144B, 16B-aligned rows)
#define PAP  72   // P-bounce row pitch in shorts (144B, 16B-aligned rows)
#define BP   33   // fallback bits row pitch in u64
#define AP   68   // fallback attn-bounce pitch in floats

__device__ __forceinline__ short f2bf(float f) {
    __hip_bfloat16 h = __float2bfloat16(f);
    return __builtin_bit_cast(short, h);
}
__device__ __forceinline__ float bf2f(short s) {
    unsigned int u = ((unsigned int)(unsigned short)s) << 16;
    return __builtin_bit_cast(float, u);
}

// raw barrier: NO implicit vmcnt/lgkm drain
__device__ __forceinline__ void barrier_raw() {
    __builtin_amdgcn_sched_barrier(0);
    __builtin_amdgcn_s_barrier();
    __builtin_amdgcn_sched_barrier(0);
}
// publish this wave's LDS writes, then barrier (still no vmcnt drain)
__device__ __forceinline__ void barrier_pub() {
    __builtin_amdgcn_sched_barrier(0);
    asm volatile("s_waitcnt lgkmcnt(0)" ::: "memory");
    __builtin_amdgcn_s_barrier();
    __builtin_amdgcn_sched_barrier(0);
}

// ============================ pre-pass kernels ============================

__global__ __launch_bounds__(256)
void conv_k_kernel(const float* __restrict__ k, short* __restrict__ kbf)
{
    size_t idx = ((size_t)blockIdx.x * 256 + threadIdx.x) * 8;
    const float* p = k + idx;
    float4 a = *(const float4*)p;
    float4 c = *(const float4*)(p + 4);
    short8 f;
    f[0]=f2bf(a.x); f[1]=f2bf(a.y); f[2]=f2bf(a.z); f[3]=f2bf(a.w);
    f[4]=f2bf(c.x); f[5]=f2bf(c.y); f[6]=f2bf(c.z); f[7]=f2bf(c.w);
    *(short8*)(kbf + idx) = f;
}

__global__ __launch_bounds__(256)
void conv_vt_kernel(const float* __restrict__ v, short* __restrict__ vtb)
{
    __shared__ float tile[64][65];
    const int t  = threadIdx.x;
    const int b  = blockIdx.x >> 5;
    const int j0 = (blockIdx.x & 31) * 64;

    #pragma unroll
    for (int p = 0; p < 4; ++p) {
        int j = (t >> 4) + p * 16;
        int d = (t & 15) * 4;
        float4 x = *(const float4*)(v + ((size_t)(b * S_LEN + j0 + j) * DIM + d));
        tile[j][d+0]=x.x; tile[j][d+1]=x.y; tile[j][d+2]=x.z; tile[j][d+3]=x.w;
    }
    __syncthreads();
    #pragma unroll
    for (int p = 0; p < 4; ++p) {
        int d  = (t >> 4) + p * 16;
        int j4 = (t & 15) * 4;
        short4b s4;
        s4[0]=f2bf(tile[j4+0][d]); s4[1]=f2bf(tile[j4+1][d]);
        s4[2]=f2bf(tile[j4+2][d]); s4[3]=f2bf(tile[j4+3][d]);
        *(short4b*)(vtb + ((size_t)(b * DIM + d) * S_LEN + j0 + j4)) = s4;
    }
}

// ============================ main kernel (R9 + bf16 bounce + 5 blk/CU) ============================

__global__ __launch_bounds__(256, 5)
void sdpa_v11(const float* __restrict__ q, const int* __restrict__ mask,
              const short* __restrict__ kbf, const short* __restrict__ vtb,
              float* __restrict__ out, float* __restrict__ attn)
{
    __shared__ __align__(16) short Klds[BR * KP];    // 9.2 KB
    __shared__ __align__(16) short Vtlds[DIM * KP];  // 9.2 KB
    __shared__ __align__(16) short Plds[BR * PAP];   // 9.2 KB  => 27.6 KB total

    const int t  = threadIdx.x;
    const int l  = t & 63;
    const int wv = t >> 6;
    const int lg = l >> 4;
    const int ll = l & 15;

    // XCD swizzle: batches 4x..4x+3 -> XCD x (K+Vt ~2MB fits its L2)
    const int bx  = blockIdx.x;
    const int kk  = bx >> 3;
    const int b   = (bx & 7) * 4 + (kk >> 5);
    const int i0  = (kk & 31) * BR;

    const float LOG2E_T = 0.18033688011112042f;   // log2(e)/8

    // staging map: thread t stages LDS row krow (16 shorts at kcol)
    const int krow = t >> 2;
    const int kcol = (t & 3) * 16;
    const size_t kgbase = (size_t)(b * S_LEN + krow) * DIM + kcol;        // + kt*BC*DIM
    const size_t vgbase = (size_t)(b * DIM + krow) * S_LEN + kcol;        // + kt*BC
    const size_t mbase  = (size_t)(b * S_LEN + i0 + 16 * wv) * S_LEN + l; // + r*S + s*128 + h*64

    // ---- Q fragments ----
    short8 qf[2];
    {
        const float* qrow = q + ((size_t)(b * S_LEN + i0 + 16 * wv + ll) * DIM);
        #pragma unroll
        for (int s = 0; s < 2; ++s) {
            const float* p = qrow + s * 32 + lg * 8;
            float4 a = *(const float4*)p;
            float4 c = *(const float4*)(p + 4);
            short8 f;
            f[0]=f2bf(a.x); f[1]=f2bf(a.y); f[2]=f2bf(a.z); f[3]=f2bf(a.w);
            f[4]=f2bf(c.x); f[5]=f2bf(c.y); f[6]=f2bf(c.z); f[7]=f2bf(c.w);
            qf[s] = f;
        }
    }

    // ---- prologue: K tile0 + mask super 0 (512B/row bursts) ----
    short8 kA0 = *(const short8*)(kbf + kgbase);
    short8 kA1 = *(const short8*)(kbf + kgbase + 8);
    short8 kB0, kB1;
    int m[32];
    #pragma unroll
    for (int r = 0; r < 16; ++r) {
        m[2*r+0] = __builtin_nontemporal_load(mask + mbase + (size_t)r * S_LEN);
        m[2*r+1] = __builtin_nontemporal_load(mask + mbase + (size_t)r * S_LEN + 64);
    }

    float rs[4] = {0.f, 0.f, 0.f, 0.f};
    unsigned long long w8[8];

    // ================= Phase 1: rowsums, mask bits -> registers =================
    for (int o = 0; o < 4; ++o) {
        #pragma unroll
        for (int ss = 0; ss < 4; ++ss) {
            const int kt0 = 8 * o + 2 * ss;
            const int sI  = 4 * o + ss;           // super index

            // ballots for both tiles of this super (loads issued 1 super ago)
            unsigned long long wb[2][4];
            #pragma unroll
            for (int r = 0; r < 16; ++r) {
                #pragma unroll
                for (int h = 0; h < 2; ++h) {
                    unsigned long long bal = __ballot(m[2*r+h] != 0);
                    if ((r >> 2) == lg) wb[h][r & 3] = bal;
                    if (lg == o && ll == r) w8[2*ss+h] = bal;
                }
            }

            // ---- inner h = 0 (tile kt0) ----
            barrier_raw();
            {
                short* kd = &Klds[krow * KP + kcol];
                *(short8*)kd = kA0;
                *(short8*)(kd + 8) = kA1;
            }
            barrier_pub();
            // issue K(kt0+1) and next mask super (512B/row) — in flight across compute
            {
                const short* kb = kbf + kgbase + (size_t)(kt0 + 1) * BC * DIM;
                kB0 = *(const short8*)kb;
                kB1 = *(const short8*)(kb + 8);
                const int sN = (sI < 15) ? sI + 1 : sI;
                const int* mp = mask + mbase + (size_t)sN * 128;
                #pragma unroll
                for (int r = 0; r < 16; ++r) {
                    m[2*r+0] = __builtin_nontemporal_load(mp + (size_t)r * S_LEN);
                    m[2*r+1] = __builtin_nontemporal_load(mp + (size_t)r * S_LEN + 64);
                }
            }
            __builtin_amdgcn_sched_barrier(0);
            #pragma unroll
            for (int jt = 0; jt < 4; ++jt) {
                short8 b0 = *(short8*)&Klds[(jt * 16 + ll) * KP + lg * 8];
                short8 b1 = *(short8*)&Klds[(jt * 16 + ll) * KP + 32 + lg * 8];
                f32x4 c = {0.f, 0.f, 0.f, 0.f};
                c = __builtin_amdgcn_mfma_f32_16x16x32_bf16(qf[0], b0, c, 0, 0, 0);
                c = __builtin_amdgcn_mfma_f32_16x16x32_bf16(qf[1], b1, c, 0, 0, 0);
                #pragma unroll
                for (int r = 0; r < 4; ++r) {
                    unsigned int bit = (unsigned int)(wb[0][r] >> (jt * 16 + ll)) & 1u;
                    rs[r] += bit ? 0.f : __builtin_amdgcn_exp2f(c[r] * LOG2E_T);
                }
            }

            // ---- inner h = 1 (tile kt0+1) ----
            barrier_raw();
            {
                short* kd = &Klds[krow * KP + kcol];
                *(short8*)kd = kB0;
                *(short8*)(kd + 8) = kB1;
            }
            barrier_pub();
            {
                const int ktn = (kt0 + 2 < NKT) ? kt0 + 2 : NKT - 1;
                const short* kb = kbf + kgbase + (size_t)ktn * BC * DIM;
                kA0 = *(const short8*)kb;
                kA1 = *(const short8*)(kb + 8);
            }
            __builtin_amdgcn_sched_barrier(0);
            #pragma unroll
            for (int jt = 0; jt < 4; ++jt) {
                short8 b0 = *(short8*)&Klds[(jt * 16 + ll) * KP + lg * 8];
                short8 b1 = *(short8*)&Klds[(jt * 16 + ll) * KP + 32 + lg * 8];
                f32x4 c = {0.f, 0.f, 0.f, 0.f};
                c = __builtin_amdgcn_mfma_f32_16x16x32_bf16(qf[0], b0, c, 0, 0, 0);
                c = __builtin_amdgcn_mfma_f32_16x16x32_bf16(qf[1], b1, c, 0, 0, 0);
                #pragma unroll
                for (int r = 0; r < 4; ++r) {
                    unsigned int bit = (unsigned int)(wb[1][r] >> (jt * 16 + ll)) & 1u;
                    rs[r] += bit ? 0.f : __builtin_amdgcn_exp2f(c[r] * LOG2E_T);
                }
            }
        }
    }

    // phase-2 tile-0 prefetch before the reduce (covers latency)
    kA0 = *(const short8*)(kbf + kgbase);
    kA1 = *(const short8*)(kbf + kgbase + 8);
    short8 vA0 = *(const short8*)(vtb + vgbase);
    short8 vA1 = *(const short8*)(vtb + vgbase + 8);
    short8 vB0, vB1;

    float inv[4];
    #pragma unroll
    for (int r = 0; r < 4; ++r) {
        float s = rs[r];
        s += __shfl_xor(s, 1);
        s += __shfl_xor(s, 2);
        s += __shfl_xor(s, 4);
        s += __shfl_xor(s, 8);
        inv[r] = 1.0f / s;
    }

    // ================= Phase 2: attn write (512B bursts) + PV =================
    f32x4 oacc[4];
    #pragma unroll
    for (int dt = 0; dt < 4; ++dt) oacc[dt] = (f32x4){0.f, 0.f, 0.f, 0.f};

    float* const abase = attn + (size_t)b * S_LEN * S_LEN;

    for (int o = 0; o < 4; ++o) {
        #pragma unroll
        for (int ss = 0; ss < 4; ++ss) {
            const int kt0 = 8 * o + 2 * ss;
            const int j0s = kt0 * BC;

            short4b pst[2][4];          // bf16-packed store staging (16 VGPR)

            #pragma unroll
            for (int h = 0; h < 2; ++h) {
                barrier_raw();
                {
                    short* kd = &Klds[krow * KP + kcol];
                    *(short8*)kd = (h ? kB0 : kA0);
                    *(short8*)(kd + 8) = (h ? kB1 : kA1);
                    short* vd = &Vtlds[krow * KP + kcol];
                    *(short8*)vd = (h ? vB0 : vA0);
                    *(short8*)(vd + 8) = (h ? vB1 : vA1);
                }
                barrier_pub();
                if (h == 0) {
                    const short* kb = kbf + kgbase + (size_t)(kt0 + 1) * BC * DIM;
                    kB0 = *(const short8*)kb;
                    kB1 = *(const short8*)(kb + 8);
                    const short* vb = vtb + vgbase + (size_t)(kt0 + 1) * BC;
                    vB0 = *(const short8*)vb;
                    vB1 = *(const short8*)(vb + 8);
                } else {
                    const int ktn = (kt0 + 2 < NKT) ? kt0 + 2 : NKT - 1;
                    const short* kb = kbf + kgbase + (size_t)ktn * BC * DIM;
                    kA0 = *(const short8*)kb;
                    kA1 = *(const short8*)(kb + 8);
                    const short* vb = vtb + vgbase + (size_t)ktn * BC;
                    vA0 = *(const short8*)vb;
                    vA1 = *(const short8*)(vb + 8);
                }
                __builtin_amdgcn_sched_barrier(0);

                unsigned long long wb[4];
                #pragma unroll
                for (int r = 0; r < 4; ++r)
                    wb[r] = __shfl(w8[2 * ss + h], 16 * o + lg * 4 + r);

                // QK^T -> normalized p (bf16) -> Plds (wave-private rows)
                #pragma unroll
                for (int jt = 0; jt < 4; ++jt) {
                    short8 b0 = *(short8*)&Klds[(jt * 16 + ll) * KP + lg * 8];
                    short8 b1 = *(short8*)&Klds[(jt * 16 + ll) * KP + 32 + lg * 8];
                    f32x4 c = {0.f, 0.f, 0.f, 0.f};
                    c = __builtin_amdgcn_mfma_f32_16x16x32_bf16(qf[0], b0, c, 0, 0, 0);
                    c = __builtin_amdgcn_mfma_f32_16x16x32_bf16(qf[1], b1, c, 0, 0, 0);
                    #pragma unroll
                    for (int r = 0; r < 4; ++r) {
                        unsigned int bit = (unsigned int)(wb[r] >> (jt * 16 + ll)) & 1u;
                        float pexp = bit ? 0.f : __builtin_amdgcn_exp2f(c[r] * LOG2E_T);
                        Plds[(16 * wv + lg * 4 + r) * PAP + jt * 16 + ll] = f2bf(pexp * inv[r]);
                    }
                }

                // PV A-fragments: direct bf16 read (no converts)
                short8 paf0 = *(short8*)&Plds[(16 * wv + ll) * PAP + lg * 8];
                short8 paf1 = *(short8*)&Plds[(16 * wv + ll) * PAP + 32 + lg * 8];

                #pragma unroll
                for (int dt = 0; dt < 4; ++dt) {
                    short8 b0 = *(short8*)&Vtlds[(dt * 16 + ll) * KP + lg * 8];
                    short8 b1 = *(short8*)&Vtlds[(dt * 16 + ll) * KP + 32 + lg * 8];
                    oacc[dt] = __builtin_amdgcn_mfma_f32_16x16x32_bf16(paf0, b0, oacc[dt], 0, 0, 0);
                    oacc[dt] = __builtin_amdgcn_mfma_f32_16x16x32_bf16(paf1, b1, oacc[dt], 0, 0, 0);
                }

                // hold this tile's store data (bf16-packed)
                #pragma unroll
                for (int ps = 0; ps < 4; ++ps) {
                    int row = 16 * wv + lg + ps * 4;
                    pst[h][ps] = *(short4b*)&Plds[row * PAP + ll * 4];
                }
            }

            // 512B-burst attn stores: per row, two adjacent 256B chunks (bf16 -> f32)
            #pragma unroll
            for (int ps = 0; ps < 4; ++ps) {
                int row = 16 * wv + lg + ps * 4;
                float* dst = abase + (size_t)(i0 + row) * S_LEN + j0s + ll * 4;
                f32x4 v0 = { bf2f(pst[0][ps][0]), bf2f(pst[0][ps][1]),
                             bf2f(pst[0][ps][2]), bf2f(pst[0][ps][3]) };
                f32x4 v1 = { bf2f(pst[1][ps][0]), bf2f(pst[1][ps][1]),
                             bf2f(pst[1][ps][2]), bf2f(pst[1][ps][3]) };
                __builtin_nontemporal_store(v0, (f32x4*)dst);
                __builtin_nontemporal_store(v1, (f32x4*)(dst + BC));
            }
        }
    }

    #pragma unroll
    for (int dt = 0; dt < 4; ++dt)
        #pragma unroll
        for (int r = 0; r < 4; ++r)
            out[(size_t)(b * S_LEN + i0 + 16 * wv + lg * 4 + r) * DIM + dt * 16 + ll] = oacc[dt][r];
}

// ============================ fallback (proven R2 kernel) ============================

__global__ __launch_bounds__(256, 3)
void sdpa_fb(const float* __restrict__ q, const float* __restrict__ k,
             const float* __restrict__ v, const int* __restrict__ mask,
             float* __restrict__ out, float* __restrict__ attn)
{
    __shared__ __align__(16) short Klds[BR * KP];
    __shared__ __align__(16) short Vtlds[DIM * KP];
    __shared__ __align__(16) unsigned long long Bits[BR * BP];
    __shared__ __align__(16) float Albs[BR * AP];

    const int t  = threadIdx.x;
    const int l  = t & 63;
    const int wv = t >> 6;
    const int lg = l >> 4;
    const int ll = l & 15;

    const int wg = blockIdx.x;
    const int b  = wg >> 5;
    const int i0 = (wg & 31) * BR;

    const float LOG2E_T = 0.18033688011112042f;

    short8 qf[2];
    {
        const float* qrow = q + ((size_t)(b * S_LEN + i0 + 16 * wv + ll) * DIM);
        #pragma unroll
        for (int s = 0; s < 2; ++s) {
            const float* p = qrow + s * 32 + lg * 8;
            float4 a = *(const float4*)p;
            float4 c = *(const float4*)(p + 4);
            short8 f;
            f[0]=f2bf(a.x); f[1]=f2bf(a.y); f[2]=f2bf(a.z); f[3]=f2bf(a.w);
            f[4]=f2bf(c.x); f[5]=f2bf(c.y); f[6]=f2bf(c.z); f[7]=f2bf(c.w);
            qf[s] = f;
        }
    }

    float rs[4] = {0.f, 0.f, 0.f, 0.f};

    for (int kt = 0; kt < NKT; ++kt) {
        const int j0 = kt * BC;
        #pragma unroll
        for (int p = 0; p < 4; ++p) {
            int row = (t >> 4) + p * 16;
            int dd  = (t & 15) * 4;
            float4 kv4 = *(const float4*)(k + ((size_t)(b * S_LEN + j0 + row) * DIM + dd));
            short4b s4;
            s4[0]=f2bf(kv4.x); s4[1]=f2bf(kv4.y); s4[2]=f2bf(kv4.z); s4[3]=f2bf(kv4.w);
            *(short4b*)&Klds[row * KP + dd] = s4;
        }
        {
            const int* mrow = mask + (size_t)(b * S_LEN + i0 + 16 * wv) * S_LEN + j0 + l;
            int mv[16];
            #pragma unroll
            for (int r = 0; r < 16; ++r)
                mv[r] = __builtin_nontemporal_load(mrow + (size_t)r * S_LEN);
            unsigned long long myword = 0ull;
            #pragma unroll
            for (int r = 0; r < 16; ++r) {
                unsigned long long bal = __ballot(mv[r] != 0);
                if (ll == r) myword = bal;
            }
            if (l < 16) Bits[(16 * wv + l) * BP + kt] = myword;
        }
        __syncthreads();

        unsigned long long wbits[4];
        #pragma unroll
        for (int r = 0; r < 4; ++r)
            wbits[r] = Bits[(16 * wv + lg * 4 + r) * BP + kt];

        #pragma unroll
        for (int jt = 0; jt < 4; ++jt) {
            short8 b0 = *(short8*)&Klds[(jt * 16 + ll) * KP + lg * 8];
            short8 b1 = *(short8*)&Klds[(jt * 16 + ll) * KP + 32 + lg * 8];
            f32x4 c = {0.f, 0.f, 0.f, 0.f};
            c = __builtin_amdgcn_mfma_f32_16x16x32_bf16(qf[0], b0, c, 0, 0, 0);
            c = __builtin_amdgcn_mfma_f32_16x16x32_bf16(qf[1], b1, c, 0, 0, 0);
            #pragma unroll
            for (int r = 0; r < 4; ++r) {
                unsigned int bit = (unsigned int)(wbits[r] >> (jt * 16 + ll)) & 1u;
                rs[r] += bit ? 0.f : __builtin_amdgcn_exp2f(c[r] * LOG2E_T);
            }
        }
        __syncthreads();
    }

    float inv[4];
    #pragma unroll
    for (int r = 0; r < 4; ++r) {
        float s = rs[r];
        s += __shfl_xor(s, 1);
        s += __shfl_xor(s, 2);
        s += __shfl_xor(s, 4);
        s += __shfl_xor(s, 8);
        inv[r] = 1.0f / s;
    }

    f32x4 oacc[4];
    #pragma unroll
    for (int dt = 0; dt < 4; ++dt) oacc[dt] = (f32x4){0.f, 0.f, 0.f, 0.f};

    for (int kt = 0; kt < NKT; ++kt) {
        const int j0 = kt * BC;
        #pragma unroll
        for (int p = 0; p < 4; ++p) {
            int row = (t >> 4) + p * 16;
            int dd  = (t & 15) * 4;
            float4 kv4 = *(const float4*)(k + ((size_t)(b * S_LEN + j0 + row) * DIM + dd));
            short4b s4;
            s4[0]=f2bf(kv4.x); s4[1]=f2bf(kv4.y); s4[2]=f2bf(kv4.z); s4[3]=f2bf(kv4.w);
            *(short4b*)&Klds[row * KP + dd] = s4;
        }
        #pragma unroll
        for (int it = 0; it < 8; ++it) {
            int jp = (t >> 4) + (it & 1) * 16;
            int dd = (t & 15) + (it >> 1) * 16;
            const float* vp = v + ((size_t)(b * S_LEN + j0 + jp * 2) * DIM + dd);
            float v0 = vp[0];
            float v1 = vp[DIM];
            unsigned int pk = (unsigned int)(unsigned short)f2bf(v0) |
                              ((unsigned int)(unsigned short)f2bf(v1) << 16);
            *(unsigned int*)&Vtlds[dd * KP + jp * 2] = pk;
        }
        __syncthreads();

        unsigned long long wbits[4];
        #pragma unroll
        for (int r = 0; r < 4; ++r)
            wbits[r] = Bits[(16 * wv + lg * 4 + r) * BP + kt];

        #pragma unroll
        for (int jt = 0; jt < 4; ++jt) {
            short8 b0 = *(short8*)&Klds[(jt * 16 + ll) * KP + lg * 8];
            short8 b1 = *(short8*)&Klds[(jt * 16 + ll) * KP + 32 + lg * 8];
            f32x4 c = {0.f, 0.f, 0.f, 0.f};
            c = __builtin_amdgcn_mfma_f32_16x16x32_bf16(qf[0], b0, c, 0, 0, 0);
            c = __builtin_amdgcn_mfma_f32_16x16x32_bf16(qf[1], b1, c, 0, 0, 0);
            #pragma unroll
            for (int r = 0; r < 4; ++r) {
                unsigned int bit = (unsigned int)(wbits[r] >> (jt * 16 + ll)) & 1u;
                float pexp = bit ? 0.f : __builtin_amdgcn_exp2f(c[r] * LOG2E_T);
                Albs[(16 * wv + lg * 4 + r) * AP + jt * 16 + ll] = pexp * inv[r];
            }
        }

        short8 paf[2];
        #pragma unroll
        for (int s = 0; s < 2; ++s) {
            const float* ap = &Albs[(16 * wv + ll) * AP + s * 32 + lg * 8];
            float4 x = *(const float4*)ap;
            float4 y = *(const float4*)(ap + 4);
            short8 f;
            f[0]=f2bf(x.x); f[1]=f2bf(x.y); f[2]=f2bf(x.z); f[3]=f2bf(x.w);
            f[4]=f2bf(y.x); f[5]=f2bf(y.y); f[6]=f2bf(y.z); f[7]=f2bf(y.w);
            paf[s] = f;
        }

        #pragma unroll
        for (int dt = 0; dt < 4; ++dt) {
            short8 b0 = *(short8*)&Vtlds[(dt * 16 + ll) * KP + lg * 8];
            short8 b1 = *(short8*)&Vtlds[(dt * 16 + ll) * KP + 32 + lg * 8];
            oacc[dt] = __builtin_amdgcn_mfma_f32_16x16x32_bf16(paf[0], b0, oacc[dt], 0, 0, 0);
            oacc[dt] = __builtin_amdgcn_mfma_f32_16x16x32_bf16(paf[1], b1, oacc[dt], 0, 0, 0);
        }

        {
            float* abase = attn + (size_t)b * S_LEN * S_LEN;
            #pragma unroll
            for (int ps = 0; ps < 4; ++ps) {
                int row = 16 * wv + lg + ps * 4;
                f32x4 val = *(f32x4*)&Albs[row * AP + ll * 4];
                float* dst = abase + (size_t)(i0 + row) * S_LEN + j0 + ll * 4;
                __builtin_nontemporal_store(val, (f32x4*)dst);
            }
        }
        __syncthreads();
    }

    #pragma unroll
    for (int dt = 0; dt < 4; ++dt)
        #pragma unroll
        for (int r = 0; r < 4; ++r)
            out[(size_t)(b * S_LEN + i0 + 16 * wv + lg * 4 + r) * DIM + dt * 16 + ll] = oacc[dt][r];
}

extern "C" void kernel_launch(void* const* d_in, const int* in_sizes, int n_in,
                              void* d_out, int out_size, void* d_ws, size_t ws_size,
                              hipStream_t stream) {
    const float* q    = (const float*)d_in[0];
    const float* k    = (const float*)d_in[1];
    const float* v    = (const float*)d_in[2];
    const int*   mask = (const int*)d_in[3];
    float* out  = (float*)d_out;
    float* attn = out + (size_t)NB * S_LEN * DIM;

    const size_t nel = (size_t)NB * S_LEN * DIM;       // 4.19M
    const size_t ws_needed = 2 * nel * sizeof(short);  // 16.8 MB

    if (ws_size >= ws_needed) {
        short* kbf = (short*)d_ws;
        short* vtb = kbf + nel;
        conv_k_kernel<<<dim3(nel / (256 * 8)), dim3(256), 0, stream>>>(k, kbf);
        conv_vt_kernel<<<dim3(NB * 32), dim3(256), 0, stream>>>(v, vtb);
        sdpa_v11<<<dim3(NB * (S_LEN / BR)), dim3(256), 0, stream>>>(q, mask, kbf, vtb, out, attn);
    } else {
        sdpa_fb<<<dim3(NB * (S_LEN / BR)), dim3(256), 0, stream>>>(q, k, v, mask, out, attn);
    }
}

// Round 12
// 269.465 us; speedup vs baseline: 1.7891x; 1.7891x over previous
//
#include <hip/hip_runtime.h>
#include <hip/hip_bf16.h>

typedef __attribute__((ext_vector_type(8))) short short8;
typedef __attribute__((ext_vector_type(4))) short short4b;
typedef __attribute__((ext_vector_type(4))) float f32x4;

#define S_LEN 2048
#define DIM   64
#define NB    32
#define BR    64
#define BC    64
#define NKT   (S_LEN / BC)   // 32

#define KP   72   // K/Vt row pitch in shorts (144B, 16B-aligned rows)
#define PAP  72   // P-bounce row pitch in shorts (144B, 16B-aligned rows)
#define BP   33   // fallback bits row pitch in u64
#define AP   68   // fallback attn-bounce pitch in floats

__device__ __forceinline__ short f2bf(float f) {
    __hip_bfloat16 h = __float2bfloat16(f);
    return __builtin_bit_cast(short, h);
}
__device__ __forceinline__ float bf2f(short s) {
    unsigned int u = ((unsigned int)(unsigned short)s) << 16;
    return __builtin_bit_cast(float, u);
}

// raw barrier: NO implicit vmcnt/lgkm drain
__device__ __forceinline__ void barrier_raw() {
    __builtin_amdgcn_sched_barrier(0);
    __builtin_amdgcn_s_barrier();
    __builtin_amdgcn_sched_barrier(0);
}
// publish this wave's LDS writes, then barrier (still no vmcnt drain)
__device__ __forceinline__ void barrier_pub() {
    __builtin_amdgcn_sched_barrier(0);
    asm volatile("s_waitcnt lgkmcnt(0)" ::: "memory");
    __builtin_amdgcn_s_barrier();
    __builtin_amdgcn_sched_barrier(0);
}

// ============================ pre-pass kernels ============================

__global__ __launch_bounds__(256)
void conv_k_kernel(const float* __restrict__ k, short* __restrict__ kbf)
{
    size_t idx = ((size_t)blockIdx.x * 256 + threadIdx.x) * 8;
    const float* p = k + idx;
    float4 a = *(const float4*)p;
    float4 c = *(const float4*)(p + 4);
    short8 f;
    f[0]=f2bf(a.x); f[1]=f2bf(a.y); f[2]=f2bf(a.z); f[3]=f2bf(a.w);
    f[4]=f2bf(c.x); f[5]=f2bf(c.y); f[6]=f2bf(c.z); f[7]=f2bf(c.w);
    *(short8*)(kbf + idx) = f;
}

__global__ __launch_bounds__(256)
void conv_vt_kernel(const float* __restrict__ v, short* __restrict__ vtb)
{
    __shared__ float tile[64][65];
    const int t  = threadIdx.x;
    const int b  = blockIdx.x >> 5;
    const int j0 = (blockIdx.x & 31) * 64;

    #pragma unroll
    for (int p = 0; p < 4; ++p) {
        int j = (t >> 4) + p * 16;
        int d = (t & 15) * 4;
        float4 x = *(const float4*)(v + ((size_t)(b * S_LEN + j0 + j) * DIM + d));
        tile[j][d+0]=x.x; tile[j][d+1]=x.y; tile[j][d+2]=x.z; tile[j][d+3]=x.w;
    }
    __syncthreads();
    #pragma unroll
    for (int p = 0; p < 4; ++p) {
        int d  = (t >> 4) + p * 16;
        int j4 = (t & 15) * 4;
        short4b s4;
        s4[0]=f2bf(tile[j4+0][d]); s4[1]=f2bf(tile[j4+1][d]);
        s4[2]=f2bf(tile[j4+2][d]); s4[3]=f2bf(tile[j4+3][d]);
        *(short4b*)(vtb + ((size_t)(b * DIM + d) * S_LEN + j0 + j4)) = s4;
    }
}

// ============================ main kernel (R9 + bf16 bounce + 1KB write bursts) ============================

__global__ __launch_bounds__(256, 4)
void sdpa_v12(const float* __restrict__ q, const int* __restrict__ mask,
              const short* __restrict__ kbf, const short* __restrict__ vtb,
              float* __restrict__ out, float* __restrict__ attn)
{
    __shared__ __align__(16) short Klds[BR * KP];    // 9.2 KB
    __shared__ __align__(16) short Vtlds[DIM * KP];  // 9.2 KB
    __shared__ __align__(16) short Plds[BR * PAP];   // 9.2 KB => 27.6 KB total

    const int t  = threadIdx.x;
    const int l  = t & 63;
    const int wv = t >> 6;
    const int lg = l >> 4;
    const int ll = l & 15;

    // XCD swizzle: batches 4x..4x+3 -> XCD x (K+Vt ~2MB fits its L2)
    const int bx  = blockIdx.x;
    const int kk  = bx >> 3;
    const int b   = (bx & 7) * 4 + (kk >> 5);
    const int i0  = (kk & 31) * BR;

    const float LOG2E_T = 0.18033688011112042f;   // log2(e)/8

    // staging map: thread t stages LDS row krow (16 shorts at kcol)
    const int krow = t >> 2;
    const int kcol = (t & 3) * 16;
    const size_t kgbase = (size_t)(b * S_LEN + krow) * DIM + kcol;        // + kt*BC*DIM
    const size_t vgbase = (size_t)(b * DIM + krow) * S_LEN + kcol;        // + kt*BC
    const size_t mbase  = (size_t)(b * S_LEN + i0 + 16 * wv) * S_LEN + l; // + r*S + s*128 + h*64

    // ---- Q fragments ----
    short8 qf[2];
    {
        const float* qrow = q + ((size_t)(b * S_LEN + i0 + 16 * wv + ll) * DIM);
        #pragma unroll
        for (int s = 0; s < 2; ++s) {
            const float* p = qrow + s * 32 + lg * 8;
            float4 a = *(const float4*)p;
            float4 c = *(const float4*)(p + 4);
            short8 f;
            f[0]=f2bf(a.x); f[1]=f2bf(a.y); f[2]=f2bf(a.z); f[3]=f2bf(a.w);
            f[4]=f2bf(c.x); f[5]=f2bf(c.y); f[6]=f2bf(c.z); f[7]=f2bf(c.w);
            qf[s] = f;
        }
    }

    // ---- prologue: K tile0 + mask super 0 (512B/row bursts) ----
    short8 kA0 = *(const short8*)(kbf + kgbase);
    short8 kA1 = *(const short8*)(kbf + kgbase + 8);
    short8 kB0, kB1;
    int m[32];
    #pragma unroll
    for (int r = 0; r < 16; ++r) {
        m[2*r+0] = __builtin_nontemporal_load(mask + mbase + (size_t)r * S_LEN);
        m[2*r+1] = __builtin_nontemporal_load(mask + mbase + (size_t)r * S_LEN + 64);
    }

    float rs[4] = {0.f, 0.f, 0.f, 0.f};
    unsigned long long w8[8];

    // ================= Phase 1: rowsums, mask bits -> registers =================
    for (int o = 0; o < 4; ++o) {
        #pragma unroll
        for (int ss = 0; ss < 4; ++ss) {
            const int kt0 = 8 * o + 2 * ss;
            const int sI  = 4 * o + ss;           // super index

            // ballots for both tiles of this super (loads issued 1 super ago)
            unsigned long long wb[2][4];
            #pragma unroll
            for (int r = 0; r < 16; ++r) {
                #pragma unroll
                for (int h = 0; h < 2; ++h) {
                    unsigned long long bal = __ballot(m[2*r+h] != 0);
                    if ((r >> 2) == lg) wb[h][r & 3] = bal;
                    if (lg == o && ll == r) w8[2*ss+h] = bal;
                }
            }

            // ---- inner h = 0 (tile kt0) ----
            barrier_raw();
            {
                short* kd = &Klds[krow * KP + kcol];
                *(short8*)kd = kA0;
                *(short8*)(kd + 8) = kA1;
            }
            barrier_pub();
            // issue K(kt0+1) and next mask super (512B/row) — in flight across compute
            {
                const short* kb = kbf + kgbase + (size_t)(kt0 + 1) * BC * DIM;
                kB0 = *(const short8*)kb;
                kB1 = *(const short8*)(kb + 8);
                const int sN = (sI < 15) ? sI + 1 : sI;
                const int* mp = mask + mbase + (size_t)sN * 128;
                #pragma unroll
                for (int r = 0; r < 16; ++r) {
                    m[2*r+0] = __builtin_nontemporal_load(mp + (size_t)r * S_LEN);
                    m[2*r+1] = __builtin_nontemporal_load(mp + (size_t)r * S_LEN + 64);
                }
            }
            __builtin_amdgcn_sched_barrier(0);
            #pragma unroll
            for (int jt = 0; jt < 4; ++jt) {
                short8 b0 = *(short8*)&Klds[(jt * 16 + ll) * KP + lg * 8];
                short8 b1 = *(short8*)&Klds[(jt * 16 + ll) * KP + 32 + lg * 8];
                f32x4 c = {0.f, 0.f, 0.f, 0.f};
                c = __builtin_amdgcn_mfma_f32_16x16x32_bf16(qf[0], b0, c, 0, 0, 0);
                c = __builtin_amdgcn_mfma_f32_16x16x32_bf16(qf[1], b1, c, 0, 0, 0);
                #pragma unroll
                for (int r = 0; r < 4; ++r) {
                    unsigned int bit = (unsigned int)(wb[0][r] >> (jt * 16 + ll)) & 1u;
                    rs[r] += bit ? 0.f : __builtin_amdgcn_exp2f(c[r] * LOG2E_T);
                }
            }

            // ---- inner h = 1 (tile kt0+1) ----
            barrier_raw();
            {
                short* kd = &Klds[krow * KP + kcol];
                *(short8*)kd = kB0;
                *(short8*)(kd + 8) = kB1;
            }
            barrier_pub();
            {
                const int ktn = (kt0 + 2 < NKT) ? kt0 + 2 : NKT - 1;
                const short* kb = kbf + kgbase + (size_t)ktn * BC * DIM;
                kA0 = *(const short8*)kb;
                kA1 = *(const short8*)(kb + 8);
            }
            __builtin_amdgcn_sched_barrier(0);
            #pragma unroll
            for (int jt = 0; jt < 4; ++jt) {
                short8 b0 = *(short8*)&Klds[(jt * 16 + ll) * KP + lg * 8];
                short8 b1 = *(short8*)&Klds[(jt * 16 + ll) * KP + 32 + lg * 8];
                f32x4 c = {0.f, 0.f, 0.f, 0.f};
                c = __builtin_amdgcn_mfma_f32_16x16x32_bf16(qf[0], b0, c, 0, 0, 0);
                c = __builtin_amdgcn_mfma_f32_16x16x32_bf16(qf[1], b1, c, 0, 0, 0);
                #pragma unroll
                for (int r = 0; r < 4; ++r) {
                    unsigned int bit = (unsigned int)(wb[1][r] >> (jt * 16 + ll)) & 1u;
                    rs[r] += bit ? 0.f : __builtin_amdgcn_exp2f(c[r] * LOG2E_T);
                }
            }
        }
    }

    // phase-2 tile-0 prefetch before the reduce (covers latency)
    kA0 = *(const short8*)(kbf + kgbase);
    kA1 = *(const short8*)(kbf + kgbase + 8);
    short8 vA0 = *(const short8*)(vtb + vgbase);
    short8 vA1 = *(const short8*)(vtb + vgbase + 8);
    short8 vB0, vB1;

    float inv[4];
    #pragma unroll
    for (int r = 0; r < 4; ++r) {
        float s = rs[r];
        s += __shfl_xor(s, 1);
        s += __shfl_xor(s, 2);
        s += __shfl_xor(s, 4);
        s += __shfl_xor(s, 8);
        inv[r] = 1.0f / s;
    }

    // ================= Phase 2: attn write (1KB bursts) + PV =================
    f32x4 oacc[4];
    #pragma unroll
    for (int dt = 0; dt < 4; ++dt) oacc[dt] = (f32x4){0.f, 0.f, 0.f, 0.f};

    float* const abase = attn + (size_t)b * S_LEN * S_LEN;

    for (int o = 0; o < 4; ++o) {
        #pragma unroll
        for (int ss = 0; ss < 2; ++ss) {
            const int kt0 = 8 * o + 4 * ss;
            const int j0s = kt0 * BC;

            short4b pst[4][4];          // bf16-packed store staging (32 VGPR)

            #pragma unroll
            for (int h = 0; h < 4; ++h) {
                const int kt = kt0 + h;

                barrier_raw();
                {
                    short* kd = &Klds[krow * KP + kcol];
                    *(short8*)kd = ((h & 1) ? kB0 : kA0);
                    *(short8*)(kd + 8) = ((h & 1) ? kB1 : kA1);
                    short* vd = &Vtlds[krow * KP + kcol];
                    *(short8*)vd = ((h & 1) ? vB0 : vA0);
                    *(short8*)(vd + 8) = ((h & 1) ? vB1 : vA1);
                }
                barrier_pub();
                // prefetch kt+1 into the other buffer (in flight across compute)
                {
                    const int ktn = (kt < NKT - 1) ? kt + 1 : kt;
                    const short* kb = kbf + kgbase + (size_t)ktn * BC * DIM;
                    const short* vb = vtb + vgbase + (size_t)ktn * BC;
                    if (h & 1) {
                        kA0 = *(const short8*)kb;
                        kA1 = *(const short8*)(kb + 8);
                        vA0 = *(const short8*)vb;
                        vA1 = *(const short8*)(vb + 8);
                    } else {
                        kB0 = *(const short8*)kb;
                        kB1 = *(const short8*)(kb + 8);
                        vB0 = *(const short8*)vb;
                        vB1 = *(const short8*)(vb + 8);
                    }
                }
                __builtin_amdgcn_sched_barrier(0);

                unsigned long long wb[4];
                #pragma unroll
                for (int r = 0; r < 4; ++r)
                    wb[r] = __shfl(w8[4 * ss + h], 16 * o + lg * 4 + r);

                // QK^T -> normalized p (bf16) -> Plds (wave-private rows)
                #pragma unroll
                for (int jt = 0; jt < 4; ++jt) {
                    short8 b0 = *(short8*)&Klds[(jt * 16 + ll) * KP + lg * 8];
                    short8 b1 = *(short8*)&Klds[(jt * 16 + ll) * KP + 32 + lg * 8];
                    f32x4 c = {0.f, 0.f, 0.f, 0.f};
                    c = __builtin_amdgcn_mfma_f32_16x16x32_bf16(qf[0], b0, c, 0, 0, 0);
                    c = __builtin_amdgcn_mfma_f32_16x16x32_bf16(qf[1], b1, c, 0, 0, 0);
                    #pragma unroll
                    for (int r = 0; r < 4; ++r) {
                        unsigned int bit = (unsigned int)(wb[r] >> (jt * 16 + ll)) & 1u;
                        float pexp = bit ? 0.f : __builtin_amdgcn_exp2f(c[r] * LOG2E_T);
                        Plds[(16 * wv + lg * 4 + r) * PAP + jt * 16 + ll] = f2bf(pexp * inv[r]);
                    }
                }

                // PV A-fragments: direct bf16 read (no converts)
                short8 paf0 = *(short8*)&Plds[(16 * wv + ll) * PAP + lg * 8];
                short8 paf1 = *(short8*)&Plds[(16 * wv + ll) * PAP + 32 + lg * 8];

                #pragma unroll
                for (int dt = 0; dt < 4; ++dt) {
                    short8 b0 = *(short8*)&Vtlds[(dt * 16 + ll) * KP + lg * 8];
                    short8 b1 = *(short8*)&Vtlds[(dt * 16 + ll) * KP + 32 + lg * 8];
                    oacc[dt] = __builtin_amdgcn_mfma_f32_16x16x32_bf16(paf0, b0, oacc[dt], 0, 0, 0);
                    oacc[dt] = __builtin_amdgcn_mfma_f32_16x16x32_bf16(paf1, b1, oacc[dt], 0, 0, 0);
                }

                // hold this tile's store data (bf16-packed)
                #pragma unroll
                for (int ps = 0; ps < 4; ++ps) {
                    int row = 16 * wv + lg + ps * 4;
                    pst[h][ps] = *(short4b*)&Plds[row * PAP + ll * 4];
                }
            }

            // 1KB-burst attn stores: per row, four adjacent 256B chunks (bf16 -> f32)
            #pragma unroll
            for (int ps = 0; ps < 4; ++ps) {
                int row = 16 * wv + lg + ps * 4;
                float* dst = abase + (size_t)(i0 + row) * S_LEN + j0s + ll * 4;
                #pragma unroll
                for (int h = 0; h < 4; ++h) {
                    f32x4 v0 = { bf2f(pst[h][ps][0]), bf2f(pst[h][ps][1]),
                                 bf2f(pst[h][ps][2]), bf2f(pst[h][ps][3]) };
                    __builtin_nontemporal_store(v0, (f32x4*)(dst + h * BC));
                }
            }
        }
    }

    #pragma unroll
    for (int dt = 0; dt < 4; ++dt)
        #pragma unroll
        for (int r = 0; r < 4; ++r)
            out[(size_t)(b * S_LEN + i0 + 16 * wv + lg * 4 + r) * DIM + dt * 16 + ll] = oacc[dt][r];
}

// ============================ fallback (proven R2 kernel) ============================

__global__ __launch_bounds__(256, 3)
void sdpa_fb(const float* __restrict__ q, const float* __restrict__ k,
             const float* __restrict__ v, const int* __restrict__ mask,
             float* __restrict__ out, float* __restrict__ attn)
{
    __shared__ __align__(16) short Klds[BR * KP];
    __shared__ __align__(16) short Vtlds[DIM * KP];
    __shared__ __align__(16) unsigned long long Bits[BR * BP];
    __shared__ __align__(16) float Albs[BR * AP];

    const int t  = threadIdx.x;
    const int l  = t & 63;
    const int wv = t >> 6;
    const int lg = l >> 4;
    const int ll = l & 15;

    const int wg = blockIdx.x;
    const int b  = wg >> 5;
    const int i0 = (wg & 31) * BR;

    const float LOG2E_T = 0.18033688011112042f;

    short8 qf[2];
    {
        const float* qrow = q + ((size_t)(b * S_LEN + i0 + 16 * wv + ll) * DIM);
        #pragma unroll
        for (int s = 0; s < 2; ++s) {
            const float* p = qrow + s * 32 + lg * 8;
            float4 a = *(const float4*)p;
            float4 c = *(const float4*)(p + 4);
            short8 f;
            f[0]=f2bf(a.x); f[1]=f2bf(a.y); f[2]=f2bf(a.z); f[3]=f2bf(a.w);
            f[4]=f2bf(c.x); f[5]=f2bf(c.y); f[6]=f2bf(c.z); f[7]=f2bf(c.w);
            qf[s] = f;
        }
    }

    float rs[4] = {0.f, 0.f, 0.f, 0.f};

    for (int kt = 0; kt < NKT; ++kt) {
        const int j0 = kt * BC;
        #pragma unroll
        for (int p = 0; p < 4; ++p) {
            int row = (t >> 4) + p * 16;
            int dd  = (t & 15) * 4;
            float4 kv4 = *(const float4*)(k + ((size_t)(b * S_LEN + j0 + row) * DIM + dd));
            short4b s4;
            s4[0]=f2bf(kv4.x); s4[1]=f2bf(kv4.y); s4[2]=f2bf(kv4.z); s4[3]=f2bf(kv4.w);
            *(short4b*)&Klds[row * KP + dd] = s4;
        }
        {
            const int* mrow = mask + (size_t)(b * S_LEN + i0 + 16 * wv) * S_LEN + j0 + l;
            int mv[16];
            #pragma unroll
            for (int r = 0; r < 16; ++r)
                mv[r] = __builtin_nontemporal_load(mrow + (size_t)r * S_LEN);
            unsigned long long myword = 0ull;
            #pragma unroll
            for (int r = 0; r < 16; ++r) {
                unsigned long long bal = __ballot(mv[r] != 0);
                if (ll == r) myword = bal;
            }
            if (l < 16) Bits[(16 * wv + l) * BP + kt] = myword;
        }
        __syncthreads();

        unsigned long long wbits[4];
        #pragma unroll
        for (int r = 0; r < 4; ++r)
            wbits[r] = Bits[(16 * wv + lg * 4 + r) * BP + kt];

        #pragma unroll
        for (int jt = 0; jt < 4; ++jt) {
            short8 b0 = *(short8*)&Klds[(jt * 16 + ll) * KP + lg * 8];
            short8 b1 = *(short8*)&Klds[(jt * 16 + ll) * KP + 32 + lg * 8];
            f32x4 c = {0.f, 0.f, 0.f, 0.f};
            c = __builtin_amdgcn_mfma_f32_16x16x32_bf16(qf[0], b0, c, 0, 0, 0);
            c = __builtin_amdgcn_mfma_f32_16x16x32_bf16(qf[1], b1, c, 0, 0, 0);
            #pragma unroll
            for (int r = 0; r < 4; ++r) {
                unsigned int bit = (unsigned int)(wbits[r] >> (jt * 16 + ll)) & 1u;
                rs[r] += bit ? 0.f : __builtin_amdgcn_exp2f(c[r] * LOG2E_T);
            }
        }
        __syncthreads();
    }

    float inv[4];
    #pragma unroll
    for (int r = 0; r < 4; ++r) {
        float s = rs[r];
        s += __shfl_xor(s, 1);
        s += __shfl_xor(s, 2);
        s += __shfl_xor(s, 4);
        s += __shfl_xor(s, 8);
        inv[r] = 1.0f / s;
    }

    f32x4 oacc[4];
    #pragma unroll
    for (int dt = 0; dt < 4; ++dt) oacc[dt] = (f32x4){0.f, 0.f, 0.f, 0.f};

    for (int kt = 0; kt < NKT; ++kt) {
        const int j0 = kt * BC;
        #pragma unroll
        for (int p = 0; p < 4; ++p) {
            int row = (t >> 4) + p * 16;
            int dd  = (t & 15) * 4;
            float4 kv4 = *(const float4*)(k + ((size_t)(b * S_LEN + j0 + row) * DIM + dd));
            short4b s4;
            s4[0]=f2bf(kv4.x); s4[1]=f2bf(kv4.y); s4[2]=f2bf(kv4.z); s4[3]=f2bf(kv4.w);
            *(short4b*)&Klds[row * KP + dd] = s4;
        }
        #pragma unroll
        for (int it = 0; it < 8; ++it) {
            int jp = (t >> 4) + (it & 1) * 16;
            int dd = (t & 15) + (it >> 1) * 16;
            const float* vp = v + ((size_t)(b * S_LEN + j0 + jp * 2) * DIM + dd);
            float v0 = vp[0];
            float v1 = vp[DIM];
            unsigned int pk = (unsigned int)(unsigned short)f2bf(v0) |
                              ((unsigned int)(unsigned short)f2bf(v1) << 16);
            *(unsigned int*)&Vtlds[dd * KP + jp * 2] = pk;
        }
        __syncthreads();

        unsigned long long wbits[4];
        #pragma unroll
        for (int r = 0; r < 4; ++r)
            wbits[r] = Bits[(16 * wv + lg * 4 + r) * BP + kt];

        #pragma unroll
        for (int jt = 0; jt < 4; ++jt) {
            short8 b0 = *(short8*)&Klds[(jt * 16 + ll) * KP + lg * 8];
            short8 b1 = *(short8*)&Klds[(jt * 16 + ll) * KP + 32 + lg * 8];
            f32x4 c = {0.f, 0.f, 0.f, 0.f};
            c = __builtin_amdgcn_mfma_f32_16x16x32_bf16(qf[0], b0, c, 0, 0, 0);
            c = __builtin_amdgcn_mfma_f32_16x16x32_bf16(qf[1], b1, c, 0, 0, 0);
            #pragma unroll
            for (int r = 0; r < 4; ++r) {
                unsigned int bit = (unsigned int)(wbits[r] >> (jt * 16 + ll)) & 1u;
                float pexp = bit ? 0.f : __builtin_amdgcn_exp2f(c[r] * LOG2E_T);
                Albs[(16 * wv + lg * 4 + r) * AP + jt * 16 + ll] = pexp * inv[r];
            }
        }

        short8 paf[2];
        #pragma unroll
        for (int s = 0; s < 2; ++s) {
            const float* ap = &Albs[(16 * wv + ll) * AP + s * 32 + lg * 8];
            float4 x = *(const float4*)ap;
            float4 y = *(const float4*)(ap + 4);
            short8 f;
            f[0]=f2bf(x.x); f[1]=f2bf(x.y); f[2]=f2bf(x.z); f[3]=f2bf(x.w);
            f[4]=f2bf(y.x); f[5]=f2bf(y.y); f[6]=f2bf(y.z); f[7]=f2bf(y.w);
            paf[s] = f;
        }

        #pragma unroll
        for (int dt = 0; dt < 4; ++dt) {
            short8 b0 = *(short8*)&Vtlds[(dt * 16 + ll) * KP + lg * 8];
            short8 b1 = *(short8*)&Vtlds[(dt * 16 + ll) * KP + 32 + lg * 8];
            oacc[dt] = __builtin_amdgcn_mfma_f32_16x16x32_bf16(paf[0], b0, oacc[dt], 0, 0, 0);
            oacc[dt] = __builtin_amdgcn_mfma_f32_16x16x32_bf16(paf[1], b1, oacc[dt], 0, 0, 0);
        }

        {
            float* abase = attn + (size_t)b * S_LEN * S_LEN;
            #pragma unroll
            for (int ps = 0; ps < 4; ++ps) {
                int row = 16 * wv + lg + ps * 4;
                f32x4 val = *(f32x4*)&Albs[row * AP + ll * 4];
                float* dst = abase + (size_t)(i0 + row) * S_LEN + j0 + ll * 4;
                __builtin_nontemporal_store(val, (f32x4*)dst);
            }
        }
        __syncthreads();
    }

    #pragma unroll
    for (int dt = 0; dt < 4; ++dt)
        #pragma unroll
        for (int r = 0; r < 4; ++r)
            out[(size_t)(b * S_LEN + i0 + 16 * wv + lg * 4 + r) * DIM + dt * 16 + ll] = oacc[dt][r];
}

extern "C" void kernel_launch(void* const* d_in, const int* in_sizes, int n_in,
                              void* d_out, int out_size, void* d_ws, size_t ws_size,
                              hipStream_t stream) {
    const float* q    = (const float*)d_in[0];
    const float* k    = (const float*)d_in[1];
    const float* v    = (const float*)d_in[2];
    const int*   mask = (const int*)d_in[3];
    float* out  = (float*)d_out;
    float* attn = out + (size_t)NB * S_LEN * DIM;

    const size_t nel = (size_t)NB * S_LEN * DIM;       // 4.19M
    const size_t ws_needed = 2 * nel * sizeof(short);  // 16.8 MB

    if (ws_size >= ws_needed) {
        short* kbf = (short*)d_ws;
        short* vtb = kbf + nel;
        conv_k_kernel<<<dim3(nel / (256 * 8)), dim3(256), 0, stream>>>(k, kbf);
        conv_vt_kernel<<<dim3(NB * 32), dim3(256), 0, stream>>>(v, vtb);
        sdpa_v12<<<dim3(NB * (S_LEN / BR)), dim3(256), 0, stream>>>(q, mask, kbf, vtb, out, attn);
    } else {
        sdpa_fb<<<dim3(NB * (S_LEN / BR)), dim3(256), 0, stream>>>(q, k, v, mask, out, attn);
    }
}